// Round 11
// baseline (131.326 us; speedup 1.0000x reference)
//
#include <hip/hip_runtime.h>
#include <math.h>

// Shapes: B=8 S=1024 IN=768 H=8 F=64 ; M=B*S=8192, N=H*F=512, K=768
// Pipeline (3 kernels):
//   conv_w   : W fp32 [768][512] -> WbT bf16 [512][768]   (transpose)
//   gemm_xw  : X fp32 x WbT -> WhT bf16 [bh][f][s] (MFMA). Tile 64x64, BK=64,
//              grid (128 m, 8 n) -> XCD = m%8. Coalesced staging (4 rows x
//              256B per wave-instr). Double-buffered LDS, 1 barrier/iter.
//              PREFETCH DEPTH 2: tile k+2's X and B loads issued at iter k ->
//              ~2 compute phases (>=600 cyc) of cover vs L2/L3 latency
//              (R9/R10 counters showed depth-1 leaves the kernel latency-
//              bound at MfmaUtil 4.7%). FUSED src/dst epilogue.
//   gat_attn : i-tile 64 (wave = 16 rows), grid (64 bh, 16 i) = 1024 blocks
//              (4/CU, 16 waves/CU - the measured-best occupancy point).
//              P-scores in MFMA A-frags; PV + l (ones-B) on the MFMA pipe;
//              double-buffered LDS, 1 barrier/tile; XCD = bh%8.

typedef __attribute__((ext_vector_type(8))) short short8;   // 8 bf16 (4 VGPRs)
typedef __attribute__((ext_vector_type(4))) float floatx4;  // MFMA C/D

union Frag { short8 s8; uint4 u4; };

__device__ inline unsigned as_u(float f) { union { float f; unsigned u; } v; v.f = f; return v.u; }
__device__ inline float as_f(unsigned u) { union { unsigned u; float f; } v; v.u = u; return v.f; }

// RNE pack two fp32 -> bf16x2 (lo = a, hi = b)
__device__ inline unsigned pk_rne(float a, float b) {
  unsigned ua = as_u(a); ua = ua + 0x7fffu + ((ua >> 16) & 1u);
  unsigned ub = as_u(b); ub = ub + 0x7fffu + ((ub >> 16) & 1u);
  return (ua >> 16) | (ub & 0xffff0000u);
}
__device__ inline unsigned short f2bf(float f) {
  unsigned u = as_u(f); u = u + 0x7fffu + ((u >> 16) & 1u);
  return (unsigned short)(u >> 16);
}

// ---------------- conv_w: transpose W (768x512 fp32) -> WbT (512x768 bf16)
__global__ __launch_bounds__(256) void conv_w(const float* __restrict__ W,
                                              unsigned short* __restrict__ WbT) {
  __shared__ unsigned short tile[64][72];  // [n][k], stride 144B (bank-friendly)
  int kt = blockIdx.x >> 3, nt = blockIdx.x & 7;
  int k0 = kt * 64, n0 = nt * 64;
  int t = threadIdx.x;
  int kr = t >> 2, cs = (t & 3) * 16;
#pragma unroll
  for (int q = 0; q < 4; q++) {
    float4 v = *(const float4*)&W[(k0 + kr) * 512 + n0 + cs + q * 4];
    tile[cs + q * 4 + 0][kr] = f2bf(v.x);
    tile[cs + q * 4 + 1][kr] = f2bf(v.y);
    tile[cs + q * 4 + 2][kr] = f2bf(v.z);
    tile[cs + q * 4 + 3][kr] = f2bf(v.w);
  }
  __syncthreads();
  int nr = t >> 2, ks = (t & 3) * 16;
  uint4 d0 = *(const uint4*)&tile[nr][ks];
  uint4 d1 = *(const uint4*)&tile[nr][ks + 8];
  *(uint4*)&WbT[(n0 + nr) * 768 + k0 + ks] = d0;
  *(uint4*)&WbT[(n0 + nr) * 768 + k0 + ks + 8] = d1;
}

// ---------------- gemm_xw: Wh = X @ W (bf16 MFMA) + fused src/dst epilogue.
// tile 64(M) x 64(N), BK=64, 12 k-iters, grid (128 m, 8 n), 256 thr = 4 waves;
// wave tile 32x32, 8 MFMA/iter. Depth-2 register prefetch (X and B).
__global__ __launch_bounds__(256) void gemm_xw(const float* __restrict__ X,
                                               const unsigned short* __restrict__ WbT,
                                               const float* __restrict__ a,
                                               const int* __restrict__ mask,
                                               unsigned short* __restrict__ WhT,
                                               float* __restrict__ srcT,
                                               float* __restrict__ dstT) {
  __shared__ unsigned short Asm[2][64 * 64];  // [buf][row][k] bf16, 8KB each
  __shared__ float sd[2][64], dd[2][64];      // fused src/dst cross-wave partials
  int t = threadIdx.x, w = t >> 6, lane = t & 63;
  int quad = lane >> 4, l15 = lane & 15;
  int m0 = blockIdx.x * 64, n0 = blockIdx.y * 64;
  int wm = (w & 1) * 32, wn = (w >> 1) * 32;

  floatx4 acc[2][2];
#pragma unroll
  for (int mt = 0; mt < 2; mt++)
#pragma unroll
    for (int nt = 0; nt < 2; nt++)
#pragma unroll
      for (int r = 0; r < 4; r++) acc[mt][nt][r] = 0.f;

  // staging: q in 0..3 -> row = (t>>4)+16q, chunk c = t&15 (16B fp32 = 4 k).
  // One wave-instr = 4 rows x 256B contiguous = 16 cache lines (optimal).
  int srow = t >> 4, c = t & 15;
  const float* xp[4];
#pragma unroll
  for (int q = 0; q < 4; q++) xp[q] = &X[(m0 + srow + 16 * q) * 768 + c * 4];
  int woff[4];  // LDS write addr (shorts): row*64 + ((c>>1)^(row&7))*8 + (c&1)*4
#pragma unroll
  for (int q = 0; q < 4; q++) {
    int r = srow + 16 * q;
    woff[q] = r * 64 + (((c >> 1) ^ (r & 7)) * 8) + (c & 1) * 4;
  }
  const unsigned short* bp0 = &WbT[(n0 + wn + l15) * 768 + quad * 8];
  const unsigned short* bp1 = &WbT[(n0 + wn + 16 + l15) * 768 + quad * 8];
  int rd0 = (wm + l15) * 64, rd1 = (wm + 16 + l15) * 64;
  int rkey0 = (wm + l15) & 7, rkey1 = (wm + 16 + l15) & 7;

  // depth-2 pipeline registers
  float4 xv[4], xn1[4], xn2[4];
  Frag fbA[2][2], fbB[2][2], fbC[2][2];  // [nt][kc2]: current / +1 / +2
#pragma unroll
  for (int q = 0; q < 4; q++) xv[q] = *(const float4*)&xp[q][0];
#pragma unroll
  for (int q = 0; q < 4; q++) xn1[q] = *(const float4*)&xp[q][64];
#pragma unroll
  for (int kc2 = 0; kc2 < 2; kc2++) {
    fbA[0][kc2] = *(const Frag*)&bp0[kc2 * 32];
    fbA[1][kc2] = *(const Frag*)&bp1[kc2 * 32];
    fbB[0][kc2] = *(const Frag*)&bp0[64 + kc2 * 32];
    fbB[1][kc2] = *(const Frag*)&bp1[64 + kc2 * 32];
  }

#pragma unroll 2
  for (int kc = 0; kc < 12; kc++) {
    unsigned short* buf = &Asm[kc & 1][0];
    // pack tile kc (xv landed >= 2 iters ago) and stage to LDS
#pragma unroll
    for (int q = 0; q < 4; q++) {
      uint2 pw;
      pw.x = pk_rne(xv[q].x, xv[q].y);
      pw.y = pk_rne(xv[q].z, xv[q].w);
      *(uint2*)&buf[woff[q]] = pw;
    }
    __syncthreads();  // nothing in flight here
    // issue tile kc+2 loads; consumed two iterations from now
    if (kc < 10) {
#pragma unroll
      for (int q = 0; q < 4; q++) xn2[q] = *(const float4*)&xp[q][(kc + 2) * 64];
#pragma unroll
      for (int kc2 = 0; kc2 < 2; kc2++) {
        fbC[0][kc2] = *(const Frag*)&bp0[(kc + 2) * 64 + kc2 * 32];
        fbC[1][kc2] = *(const Frag*)&bp1[(kc + 2) * 64 + kc2 * 32];
      }
    }
    // MFMA on tile kc
#pragma unroll
    for (int kc2 = 0; kc2 < 2; kc2++) {
      int kb = kc2 * 4 + quad;
      Frag fa0 = *(const Frag*)&buf[rd0 + (kb ^ rkey0) * 8];
      Frag fa1 = *(const Frag*)&buf[rd1 + (kb ^ rkey1) * 8];
      acc[0][0] = __builtin_amdgcn_mfma_f32_16x16x32_bf16(fa0.s8, fbA[0][kc2].s8, acc[0][0], 0, 0, 0);
      acc[0][1] = __builtin_amdgcn_mfma_f32_16x16x32_bf16(fa0.s8, fbA[1][kc2].s8, acc[0][1], 0, 0, 0);
      acc[1][0] = __builtin_amdgcn_mfma_f32_16x16x32_bf16(fa1.s8, fbA[0][kc2].s8, acc[1][0], 0, 0, 0);
      acc[1][1] = __builtin_amdgcn_mfma_f32_16x16x32_bf16(fa1.s8, fbA[1][kc2].s8, acc[1][1], 0, 0, 0);
    }
    // rotate pipeline
#pragma unroll
    for (int q = 0; q < 4; q++) { xv[q] = xn1[q]; xn1[q] = xn2[q]; }
#pragma unroll
    for (int kc2 = 0; kc2 < 2; kc2++) {
      fbA[0][kc2] = fbB[0][kc2]; fbA[1][kc2] = fbB[1][kc2];
      fbB[0][kc2] = fbC[0][kc2]; fbB[1][kc2] = fbC[1][kc2];
    }
  }
  int h = n0 >> 6;  // n-tile is 64-aligned: whole block is one head
  // ---- store WhT: D row = quad*4+r (m), col = l15 (f); 4 consecutive s as bf16x4
#pragma unroll
  for (int mt = 0; mt < 2; mt++) {
#pragma unroll
    for (int nt = 0; nt < 2; nt++) {
      int f = (wn + nt * 16 + l15) & 63;
      int m = m0 + wm + mt * 16 + quad * 4;
      int b = m >> 10, s = m & 1023;
      floatx4 cc = acc[mt][nt];
      uint2 st;
      st.x = pk_rne(cc[0], cc[1]);
      st.y = pk_rne(cc[2], cc[3]);
      *(uint2*)&WhT[((b * 8 + h) * 64 + f) * 1024 + s] = st;
    }
  }
  // ---- fused src/dst: reduce over l15 lanes, then the 2 wn-halves via LDS
  {
    float asv[2] = {a[wn + l15], a[wn + 16 + l15]};
    float adv[2] = {a[64 + wn + l15], a[64 + wn + 16 + l15]};
    float psrc[2][4], pdst[2][4];
#pragma unroll
    for (int mt = 0; mt < 2; mt++)
#pragma unroll
      for (int r = 0; r < 4; r++) {
        psrc[mt][r] = acc[mt][0][r] * asv[0] + acc[mt][1][r] * asv[1];
        pdst[mt][r] = acc[mt][0][r] * adv[0] + acc[mt][1][r] * adv[1];
      }
#pragma unroll
    for (int off = 1; off < 16; off <<= 1)
#pragma unroll
      for (int mt = 0; mt < 2; mt++)
#pragma unroll
        for (int r = 0; r < 4; r++) {
          psrc[mt][r] += __shfl_xor(psrc[mt][r], off);
          pdst[mt][r] += __shfl_xor(pdst[mt][r], off);
        }
    __syncthreads();
    if (l15 == 0) {
      int half = w >> 1;
#pragma unroll
      for (int mt = 0; mt < 2; mt++)
#pragma unroll
        for (int r = 0; r < 4; r++) {
          int m = wm + mt * 16 + quad * 4 + r;
          sd[half][m] = psrc[mt][r];
          dd[half][m] = pdst[mt][r];
        }
    }
    __syncthreads();
    if (t < 64) {
      int m = m0 + t;
      int b = m >> 10, s = m & 1023;
      float sv = sd[0][t] + sd[1][t];
      float dvv = dd[0][t] + dd[1][t];
      srcT[(b * 8 + h) * 1024 + s] = sv;
      dstT[(b * 8 + h) * 1024 + s] = mask[b * 1024 + s] ? dvv : -1e30f;
    }
  }
}

// ---------------- gat_attn: i-tile 64, wave = 16 rows, 4 blocks/CU.
// grid (64 bh, 16 i) = 1024 blocks -> XCD = bh%8 (Wh slice L2-local);
// 256 thr = 4 waves -> 16 waves/CU. Double-buffered LDS, ONE barrier per
// tile, loads never in flight at a barrier. l via ones-B MFMA (sums exactly
// the bf16-truncated p; lacc rows = acc rows). |e|<~1 so exp can't overflow;
// mask pre-folded into dstT as -1e30.
__global__ __launch_bounds__(256) void gat_attn(const unsigned short* __restrict__ WhT,
                                                const float* __restrict__ srcT,
                                                const float* __restrict__ dstT,
                                                float* __restrict__ out) {
  __shared__ unsigned short Bs[2][64 * 64];  // [buf][f][j] bf16, swizzle pb = kb^(f&7)
  int t = threadIdx.x, w = t >> 6, lane = t & 63;
  int quad = lane >> 4, l15 = lane & 15;
  int bh = blockIdx.x, b = bh >> 3;
  int iw = blockIdx.y * 64 + w * 16;

  floatx4 acc[4], lacc;
#pragma unroll
  for (int ft = 0; ft < 4; ft++)
#pragma unroll
    for (int r = 0; r < 4; r++) acc[ft][r] = 0.f;
#pragma unroll
  for (int r = 0; r < 4; r++) lacc[r] = 0.f;

  float src_r = srcT[bh * 1024 + iw + l15];

  Frag ones;
  ones.u4.x = 0x3F803F80u; ones.u4.y = 0x3F803F80u;
  ones.u4.z = 0x3F803F80u; ones.u4.w = 0x3F803F80u;

  const unsigned short* Wg = WhT + bh * 64 * 1024;
  const float* dbase = &dstT[bh * 1024 + quad * 8];
  int sf0 = t >> 3, skb = t & 7;    // staging: f rows {sf0, sf0+32}, 16B block idx
  int swz = (skb ^ (sf0 & 7)) * 8;  // (sf0+32)&7 == sf0&7

  // preload tile 0
  uint4 g0 = *(const uint4*)&Wg[sf0 * 1024 + skb * 8];
  uint4 g1 = *(const uint4*)&Wg[(sf0 + 32) * 1024 + skb * 8];
  float4 dv[4];
  dv[0] = *(const float4*)&dbase[0];
  dv[1] = *(const float4*)&dbase[4];
  dv[2] = *(const float4*)&dbase[32];
  dv[3] = *(const float4*)&dbase[36];

#pragma unroll 2
  for (int jt = 0; jt < 16; jt++) {
    int j0 = jt * 64;
    unsigned short* buf = &Bs[jt & 1][0];
    // stage tile jt (g landed during the previous iter's scores+MFMA)
    *(uint4*)&buf[sf0 * 64 + swz] = g0;
    *(uint4*)&buf[(sf0 + 32) * 64 + swz] = g1;
    __syncthreads();  // nothing in flight here
    // issue tile jt+1 loads; consumed before the NEXT barrier
    float4 ndv[4] = {dv[0], dv[1], dv[2], dv[3]};
    if (jt < 15) {
      g0 = *(const uint4*)&Wg[sf0 * 1024 + j0 + 64 + skb * 8];
      g1 = *(const uint4*)&Wg[(sf0 + 32) * 1024 + j0 + 64 + skb * 8];
      ndv[0] = *(const float4*)&dbase[j0 + 64];
      ndv[1] = *(const float4*)&dbase[j0 + 68];
      ndv[2] = *(const float4*)&dbase[j0 + 96];
      ndv[3] = *(const float4*)&dbase[j0 + 100];
    }
    // scores tile jt -> A-fragments (VALU; covers the just-issued loads)
    Frag fragA[2];
#pragma unroll
    for (int jc = 0; jc < 2; jc++) {
      float dj[8] = {dv[jc * 2].x, dv[jc * 2].y, dv[jc * 2].z, dv[jc * 2].w,
                     dv[jc * 2 + 1].x, dv[jc * 2 + 1].y, dv[jc * 2 + 1].z, dv[jc * 2 + 1].w};
      unsigned pw[4];
#pragma unroll
      for (int pr = 0; pr < 4; pr++) {
        float x0 = src_r + dj[pr * 2];
        float x1 = src_r + dj[pr * 2 + 1];
        x0 = fmaxf(x0, 0.2f * x0);  // leaky_relu (alpha<1)
        x1 = fmaxf(x1, 0.2f * x1);
        float p0 = __expf(x0), p1 = __expf(x1);
        pw[pr] = __builtin_amdgcn_perm(as_u(p1), as_u(p0), 0x07060302u);  // bf16x2
      }
      fragA[jc].u4.x = pw[0];
      fragA[jc].u4.y = pw[1];
      fragA[jc].u4.z = pw[2];
      fragA[jc].u4.w = pw[3];
    }
    // MFMA tile jt: acc[ft] += P(16x32) x Wh(32x16) ; lacc += P x ones
#pragma unroll
    for (int jc = 0; jc < 2; jc++) {
      Frag fbr[4];
#pragma unroll
      for (int ft = 0; ft < 4; ft++) {
        int f = ft * 16 + l15;
        int kb = jc * 4 + quad;
        fbr[ft] = *(const Frag*)&buf[f * 64 + (kb ^ (f & 7)) * 8];
      }
#pragma unroll
      for (int ft = 0; ft < 4; ft++)
        acc[ft] = __builtin_amdgcn_mfma_f32_16x16x32_bf16(fragA[jc].s8, fbr[ft].s8,
                                                          acc[ft], 0, 0, 0);
      lacc = __builtin_amdgcn_mfma_f32_16x16x32_bf16(fragA[jc].s8, ones.s8, lacc, 0, 0, 0);
    }
#pragma unroll
    for (int q = 0; q < 4; q++) dv[q] = ndv[q];
  }
  // epilogue: C row = quad*4+r, col = l15; lacc rows align with acc rows
  float inv[4] = {1.f / lacc[0], 1.f / lacc[1], 1.f / lacc[2], 1.f / lacc[3]};
  int mrow = b * 1024 + iw + quad * 4;
#pragma unroll
  for (int ft = 0; ft < 4; ft++) {
    int col = (bh & 7) * 64 + ft * 16 + l15;
#pragma unroll
    for (int r = 0; r < 4; r++)
      out[(mrow + r) * 512 + col] = acc[ft][r] * inv[r];
  }
}

extern "C" void kernel_launch(void* const* d_in, const int* in_sizes, int n_in,
                              void* d_out, int out_size, void* d_ws, size_t ws_size,
                              hipStream_t stream) {
  const float* X = (const float*)d_in[0];   // (8,1024,768)
  const int* mask = (const int*)d_in[1];    // (8,1024)
  const float* W = (const float*)d_in[2];   // (768,512)
  const float* a = (const float*)d_in[3];   // (128,)
  float* out = (float*)d_out;               // (8,1024,512)

  char* ws = (char*)d_ws;
  unsigned short* WhT = (unsigned short*)ws;                    // 64*64*1024 bf16 = 8388608 B
  unsigned short* WbT = (unsigned short*)(ws + 8388608);        // 512*768 bf16  = 786432 B
  float* srcT = (float*)(ws + 9175040);                         // 64*1024 f32   = 262144 B
  float* dstT = (float*)(ws + 9437184);                         // 64*1024 f32

  conv_w<<<96, 256, 0, stream>>>(W, WbT);
  gemm_xw<<<dim3(128, 8), 256, 0, stream>>>(X, WbT, a, mask, WhT, srcT, dstT);
  gat_attn<<<dim3(64, 16), 256, 0, stream>>>(WhT, srcT, dstT, out);
}

// Round 12
// 118.134 us; speedup vs baseline: 1.1117x; 1.1117x over previous
//
#include <hip/hip_runtime.h>
#include <math.h>

// Shapes: B=8 S=1024 IN=768 H=8 F=64 ; M=B*S=8192, N=H*F=512, K=768
// Pipeline (4 kernels):
//   conv_w   : W fp32 [768][512] -> WbT bf16 [512][768]   (transpose)
//   xconv    : X fp32 -> Xb bf16 row-major (pure streaming; moves the fp32->
//              bf16 pack OUT of the gemm inner loop)
//   gemm_xw  : Xb x WbT -> WhT bf16 [bh][f][s] (MFMA). Tile 64x64, BK=64.
//              BOTH operands staged through double-buffered LDS with the
//              attn kernel's measured-conflict-free pattern (8 rows x 128B
//              per wave-instr, XOR-swizzled 16B blocks), ONE barrier/iter,
//              depth-1 staging regs. R5-R11 lesson: global->MFMA-operand
//              register pipelines stall (vmcnt in-order + rotation chains);
//              global->LDS->frag does not. FUSED src/dst epilogue.
//              Grid (128 m, 8 n) -> XCD = m%8.
//   gat_attn : i-tile 64 (wave = 16 rows), grid (64 bh, 16 i) = 1024 blocks
//              (4/CU, 16 waves/CU - measured-best). P-scores in MFMA A-frags;
//              PV + l (ones-B) on the MFMA pipe; double-buffered LDS,
//              1 barrier/tile; XCD = bh%8.

typedef __attribute__((ext_vector_type(8))) short short8;   // 8 bf16 (4 VGPRs)
typedef __attribute__((ext_vector_type(4))) float floatx4;  // MFMA C/D

union Frag { short8 s8; uint4 u4; };

__device__ inline unsigned as_u(float f) { union { float f; unsigned u; } v; v.f = f; return v.u; }
__device__ inline float as_f(unsigned u) { union { unsigned u; float f; } v; v.u = u; return v.f; }

// RNE pack two fp32 -> bf16x2 (lo = a, hi = b)
__device__ inline unsigned pk_rne(float a, float b) {
  unsigned ua = as_u(a); ua = ua + 0x7fffu + ((ua >> 16) & 1u);
  unsigned ub = as_u(b); ub = ub + 0x7fffu + ((ub >> 16) & 1u);
  return (ua >> 16) | (ub & 0xffff0000u);
}
__device__ inline unsigned short f2bf(float f) {
  unsigned u = as_u(f); u = u + 0x7fffu + ((u >> 16) & 1u);
  return (unsigned short)(u >> 16);
}

// ---------------- conv_w: transpose W (768x512 fp32) -> WbT (512x768 bf16)
__global__ __launch_bounds__(256) void conv_w(const float* __restrict__ W,
                                              unsigned short* __restrict__ WbT) {
  __shared__ unsigned short tile[64][72];  // [n][k], stride 144B (bank-friendly)
  int kt = blockIdx.x >> 3, nt = blockIdx.x & 7;
  int k0 = kt * 64, n0 = nt * 64;
  int t = threadIdx.x;
  int kr = t >> 2, cs = (t & 3) * 16;
#pragma unroll
  for (int q = 0; q < 4; q++) {
    float4 v = *(const float4*)&W[(k0 + kr) * 512 + n0 + cs + q * 4];
    tile[cs + q * 4 + 0][kr] = f2bf(v.x);
    tile[cs + q * 4 + 1][kr] = f2bf(v.y);
    tile[cs + q * 4 + 2][kr] = f2bf(v.z);
    tile[cs + q * 4 + 3][kr] = f2bf(v.w);
  }
  __syncthreads();
  int nr = t >> 2, ks = (t & 3) * 16;
  uint4 d0 = *(const uint4*)&tile[nr][ks];
  uint4 d1 = *(const uint4*)&tile[nr][ks + 8];
  *(uint4*)&WbT[(n0 + nr) * 768 + k0 + ks] = d0;
  *(uint4*)&WbT[(n0 + nr) * 768 + k0 + ks + 8] = d1;
}

// ---------------- xconv: X fp32 (8192x768) -> Xb bf16 row-major. Streaming.
__global__ __launch_bounds__(256) void xconv(const float* __restrict__ X,
                                             unsigned short* __restrict__ Xb) {
  const int total = 8192 * 768 / 8;  // 786432 uint4 outputs
  int stride = gridDim.x * 256;
  for (int i = blockIdx.x * 256 + threadIdx.x; i < total; i += stride) {
    float4 v0 = *(const float4*)&X[i * 8];
    float4 v1 = *(const float4*)&X[i * 8 + 4];
    uint4 o;
    o.x = pk_rne(v0.x, v0.y); o.y = pk_rne(v0.z, v0.w);
    o.z = pk_rne(v1.x, v1.y); o.w = pk_rne(v1.z, v1.w);
    *(uint4*)&Xb[i * 8] = o;
  }
}

// ---------------- gemm_xw: Wh = Xb @ W (bf16 MFMA) + fused src/dst epilogue.
// tile 64(M) x 64(N), BK=64, 12 k-iters, grid (128 m, 8 n), 256 thr = 4 waves;
// wave tile 32x32, 8 MFMA/iter. A and B both staged via double-buffered LDS
// (attn-pattern: thread t -> rows {t>>3, (t>>3)+32}, 16B block t&7, physical
// block = (t&7) ^ (row&7); one wave-instr = 8 rows x 128B contiguous global).
__global__ __launch_bounds__(256) void gemm_xw(const unsigned short* __restrict__ Xb,
                                               const unsigned short* __restrict__ WbT,
                                               const float* __restrict__ a,
                                               const int* __restrict__ mask,
                                               unsigned short* __restrict__ WhT,
                                               float* __restrict__ srcT,
                                               float* __restrict__ dstT) {
  __shared__ unsigned short Asm[2][64 * 64];  // [buf][m][k] bf16, 8KB each
  __shared__ unsigned short Bsm[2][64 * 64];  // [buf][n][k] bf16, 8KB each
  __shared__ float sd[2][64], dd[2][64];      // fused src/dst cross-wave partials
  int t = threadIdx.x, w = t >> 6, lane = t & 63;
  int quad = lane >> 4, l15 = lane & 15;
  int m0 = blockIdx.x * 64, n0 = blockIdx.y * 64;
  int wm = (w & 1) * 32, wn = (w >> 1) * 32;

  floatx4 acc[2][2];
#pragma unroll
  for (int mt = 0; mt < 2; mt++)
#pragma unroll
    for (int nt = 0; nt < 2; nt++)
#pragma unroll
      for (int r = 0; r < 4; r++) acc[mt][nt][r] = 0.f;

  int sf = t >> 3, skb = t & 7;     // staging rows {sf, sf+32}, 16B block skb
  int swz = (skb ^ (sf & 7)) * 8;   // (sf+32)&7 == sf&7
  const unsigned short* ga0 = &Xb[(m0 + sf) * 768 + skb * 8];
  const unsigned short* ga1 = &Xb[(m0 + sf + 32) * 768 + skb * 8];
  const unsigned short* gb0 = &WbT[(n0 + sf) * 768 + skb * 8];
  const unsigned short* gb1 = &WbT[(n0 + sf + 32) * 768 + skb * 8];

  int rdA0 = (wm + l15) * 64, rdA1 = (wm + 16 + l15) * 64;
  int keyA0 = (wm + l15) & 7, keyA1 = (wm + 16 + l15) & 7;
  int rdB0 = (wn + l15) * 64, rdB1 = (wn + 16 + l15) * 64;
  int keyB0 = (wn + l15) & 7, keyB1 = (wn + 16 + l15) & 7;

  // preload tile 0
  uint4 av0 = *(const uint4*)&ga0[0];
  uint4 av1 = *(const uint4*)&ga1[0];
  uint4 bv0 = *(const uint4*)&gb0[0];
  uint4 bv1 = *(const uint4*)&gb1[0];

#pragma unroll 2
  for (int kc = 0; kc < 12; kc++) {
    unsigned short* bufA = &Asm[kc & 1][0];
    unsigned short* bufB = &Bsm[kc & 1][0];
    // stage tile kc (regs landed during the previous iter's MFMA phase)
    *(uint4*)&bufA[sf * 64 + swz] = av0;
    *(uint4*)&bufA[(sf + 32) * 64 + swz] = av1;
    *(uint4*)&bufB[sf * 64 + swz] = bv0;
    *(uint4*)&bufB[(sf + 32) * 64 + swz] = bv1;
    __syncthreads();  // nothing in flight here
    // issue tile kc+1 loads; consumed at the top of the next iteration
    if (kc < 11) {
      int off = (kc + 1) * 64;
      av0 = *(const uint4*)&ga0[off];
      av1 = *(const uint4*)&ga1[off];
      bv0 = *(const uint4*)&gb0[off];
      bv1 = *(const uint4*)&gb1[off];
    }
    // MFMA on tile kc (all operands from LDS)
#pragma unroll
    for (int kc2 = 0; kc2 < 2; kc2++) {
      int kb = kc2 * 4 + quad;
      Frag fa0 = *(const Frag*)&bufA[rdA0 + ((kb ^ keyA0) * 8)];
      Frag fa1 = *(const Frag*)&bufA[rdA1 + ((kb ^ keyA1) * 8)];
      Frag fb0 = *(const Frag*)&bufB[rdB0 + ((kb ^ keyB0) * 8)];
      Frag fb1 = *(const Frag*)&bufB[rdB1 + ((kb ^ keyB1) * 8)];
      acc[0][0] = __builtin_amdgcn_mfma_f32_16x16x32_bf16(fa0.s8, fb0.s8, acc[0][0], 0, 0, 0);
      acc[0][1] = __builtin_amdgcn_mfma_f32_16x16x32_bf16(fa0.s8, fb1.s8, acc[0][1], 0, 0, 0);
      acc[1][0] = __builtin_amdgcn_mfma_f32_16x16x32_bf16(fa1.s8, fb0.s8, acc[1][0], 0, 0, 0);
      acc[1][1] = __builtin_amdgcn_mfma_f32_16x16x32_bf16(fa1.s8, fb1.s8, acc[1][1], 0, 0, 0);
    }
  }
  int h = n0 >> 6;  // n-tile is 64-aligned: whole block is one head
  // ---- store WhT: D row = quad*4+r (m), col = l15 (f); 4 consecutive s as bf16x4
#pragma unroll
  for (int mt = 0; mt < 2; mt++) {
#pragma unroll
    for (int nt = 0; nt < 2; nt++) {
      int f = (wn + nt * 16 + l15) & 63;
      int m = m0 + wm + mt * 16 + quad * 4;
      int b = m >> 10, s = m & 1023;
      floatx4 cc = acc[mt][nt];
      uint2 st;
      st.x = pk_rne(cc[0], cc[1]);
      st.y = pk_rne(cc[2], cc[3]);
      *(uint2*)&WhT[((b * 8 + h) * 64 + f) * 1024 + s] = st;
    }
  }
  // ---- fused src/dst: reduce over l15 lanes, then the 2 wn-halves via LDS
  {
    float asv[2] = {a[wn + l15], a[wn + 16 + l15]};
    float adv[2] = {a[64 + wn + l15], a[64 + wn + 16 + l15]};
    float psrc[2][4], pdst[2][4];
#pragma unroll
    for (int mt = 0; mt < 2; mt++)
#pragma unroll
      for (int r = 0; r < 4; r++) {
        psrc[mt][r] = acc[mt][0][r] * asv[0] + acc[mt][1][r] * asv[1];
        pdst[mt][r] = acc[mt][0][r] * adv[0] + acc[mt][1][r] * adv[1];
      }
#pragma unroll
    for (int off = 1; off < 16; off <<= 1)
#pragma unroll
      for (int mt = 0; mt < 2; mt++)
#pragma unroll
        for (int r = 0; r < 4; r++) {
          psrc[mt][r] += __shfl_xor(psrc[mt][r], off);
          pdst[mt][r] += __shfl_xor(pdst[mt][r], off);
        }
    __syncthreads();
    if (l15 == 0) {
      int half = w >> 1;
#pragma unroll
      for (int mt = 0; mt < 2; mt++)
#pragma unroll
        for (int r = 0; r < 4; r++) {
          int m = wm + mt * 16 + quad * 4 + r;
          sd[half][m] = psrc[mt][r];
          dd[half][m] = pdst[mt][r];
        }
    }
    __syncthreads();
    if (t < 64) {
      int m = m0 + t;
      int b = m >> 10, s = m & 1023;
      float sv = sd[0][t] + sd[1][t];
      float dvv = dd[0][t] + dd[1][t];
      srcT[(b * 8 + h) * 1024 + s] = sv;
      dstT[(b * 8 + h) * 1024 + s] = mask[b * 1024 + s] ? dvv : -1e30f;
    }
  }
}

// ---------------- gat_attn: i-tile 64, wave = 16 rows, 4 blocks/CU (R10 best).
// grid (64 bh, 16 i) = 1024 blocks -> XCD = bh%8 (Wh slice L2-local);
// 256 thr = 4 waves -> 16 waves/CU. Double-buffered LDS, ONE barrier per
// tile, loads never in flight at a barrier. l via ones-B MFMA (sums exactly
// the bf16-truncated p; lacc rows = acc rows). |e|<~1 so exp can't overflow;
// mask pre-folded into dstT as -1e30.
__global__ __launch_bounds__(256) void gat_attn(const unsigned short* __restrict__ WhT,
                                                const float* __restrict__ srcT,
                                                const float* __restrict__ dstT,
                                                float* __restrict__ out) {
  __shared__ unsigned short Bs[2][64 * 64];  // [buf][f][j] bf16, swizzle pb = kb^(f&7)
  int t = threadIdx.x, w = t >> 6, lane = t & 63;
  int quad = lane >> 4, l15 = lane & 15;
  int bh = blockIdx.x, b = bh >> 3;
  int iw = blockIdx.y * 64 + w * 16;

  floatx4 acc[4], lacc;
#pragma unroll
  for (int ft = 0; ft < 4; ft++)
#pragma unroll
    for (int r = 0; r < 4; r++) acc[ft][r] = 0.f;
#pragma unroll
  for (int r = 0; r < 4; r++) lacc[r] = 0.f;

  float src_r = srcT[bh * 1024 + iw + l15];

  Frag ones;
  ones.u4.x = 0x3F803F80u; ones.u4.y = 0x3F803F80u;
  ones.u4.z = 0x3F803F80u; ones.u4.w = 0x3F803F80u;

  const unsigned short* Wg = WhT + bh * 64 * 1024;
  const float* dbase = &dstT[bh * 1024 + quad * 8];
  int sf0 = t >> 3, skb = t & 7;    // staging: f rows {sf0, sf0+32}, 16B block idx
  int swz = (skb ^ (sf0 & 7)) * 8;  // (sf0+32)&7 == sf0&7

  // preload tile 0
  uint4 g0 = *(const uint4*)&Wg[sf0 * 1024 + skb * 8];
  uint4 g1 = *(const uint4*)&Wg[(sf0 + 32) * 1024 + skb * 8];
  float4 dv[4];
  dv[0] = *(const float4*)&dbase[0];
  dv[1] = *(const float4*)&dbase[4];
  dv[2] = *(const float4*)&dbase[32];
  dv[3] = *(const float4*)&dbase[36];

#pragma unroll 2
  for (int jt = 0; jt < 16; jt++) {
    int j0 = jt * 64;
    unsigned short* buf = &Bs[jt & 1][0];
    // stage tile jt (g landed during the previous iter's scores+MFMA)
    *(uint4*)&buf[sf0 * 64 + swz] = g0;
    *(uint4*)&buf[(sf0 + 32) * 64 + swz] = g1;
    __syncthreads();  // nothing in flight here
    // issue tile jt+1 loads; consumed before the NEXT barrier
    float4 ndv[4] = {dv[0], dv[1], dv[2], dv[3]};
    if (jt < 15) {
      g0 = *(const uint4*)&Wg[sf0 * 1024 + j0 + 64 + skb * 8];
      g1 = *(const uint4*)&Wg[(sf0 + 32) * 1024 + j0 + 64 + skb * 8];
      ndv[0] = *(const float4*)&dbase[j0 + 64];
      ndv[1] = *(const float4*)&dbase[j0 + 68];
      ndv[2] = *(const float4*)&dbase[j0 + 96];
      ndv[3] = *(const float4*)&dbase[j0 + 100];
    }
    // scores tile jt -> A-fragments (VALU; covers the just-issued loads)
    Frag fragA[2];
#pragma unroll
    for (int jc = 0; jc < 2; jc++) {
      float dj[8] = {dv[jc * 2].x, dv[jc * 2].y, dv[jc * 2].z, dv[jc * 2].w,
                     dv[jc * 2 + 1].x, dv[jc * 2 + 1].y, dv[jc * 2 + 1].z, dv[jc * 2 + 1].w};
      unsigned pw[4];
#pragma unroll
      for (int pr = 0; pr < 4; pr++) {
        float x0 = src_r + dj[pr * 2];
        float x1 = src_r + dj[pr * 2 + 1];
        x0 = fmaxf(x0, 0.2f * x0);  // leaky_relu (alpha<1)
        x1 = fmaxf(x1, 0.2f * x1);
        float p0 = __expf(x0), p1 = __expf(x1);
        pw[pr] = __builtin_amdgcn_perm(as_u(p1), as_u(p0), 0x07060302u);  // bf16x2
      }
      fragA[jc].u4.x = pw[0];
      fragA[jc].u4.y = pw[1];
      fragA[jc].u4.z = pw[2];
      fragA[jc].u4.w = pw[3];
    }
    // MFMA tile jt: acc[ft] += P(16x32) x Wh(32x16) ; lacc += P x ones
#pragma unroll
    for (int jc = 0; jc < 2; jc++) {
      Frag fbr[4];
#pragma unroll
      for (int ft = 0; ft < 4; ft++) {
        int f = ft * 16 + l15;
        int kb = jc * 4 + quad;
        fbr[ft] = *(const Frag*)&buf[f * 64 + (kb ^ (f & 7)) * 8];
      }
#pragma unroll
      for (int ft = 0; ft < 4; ft++)
        acc[ft] = __builtin_amdgcn_mfma_f32_16x16x32_bf16(fragA[jc].s8, fbr[ft].s8,
                                                          acc[ft], 0, 0, 0);
      lacc = __builtin_amdgcn_mfma_f32_16x16x32_bf16(fragA[jc].s8, ones.s8, lacc, 0, 0, 0);
    }
#pragma unroll
    for (int q = 0; q < 4; q++) dv[q] = ndv[q];
  }
  // epilogue: C row = quad*4+r, col = l15; lacc rows align with acc rows
  float inv[4] = {1.f / lacc[0], 1.f / lacc[1], 1.f / lacc[2], 1.f / lacc[3]};
  int mrow = b * 1024 + iw + quad * 4;
#pragma unroll
  for (int ft = 0; ft < 4; ft++) {
    int col = (bh & 7) * 64 + ft * 16 + l15;
#pragma unroll
    for (int r = 0; r < 4; r++)
      out[(mrow + r) * 512 + col] = acc[ft][r] * inv[r];
  }
}

extern "C" void kernel_launch(void* const* d_in, const int* in_sizes, int n_in,
                              void* d_out, int out_size, void* d_ws, size_t ws_size,
                              hipStream_t stream) {
  const float* X = (const float*)d_in[0];   // (8,1024,768)
  const int* mask = (const int*)d_in[1];    // (8,1024)
  const float* W = (const float*)d_in[2];   // (768,512)
  const float* a = (const float*)d_in[3];   // (128,)
  float* out = (float*)d_out;               // (8,1024,512)

  char* ws = (char*)d_ws;
  unsigned short* WhT = (unsigned short*)ws;                    // 64*64*1024 bf16 = 8388608 B
  unsigned short* WbT = (unsigned short*)(ws + 8388608);        // 512*768 bf16  = 786432 B
  float* srcT = (float*)(ws + 9175040);                         // 64*1024 f32   = 262144 B
  float* dstT = (float*)(ws + 9437184);                         // 64*1024 f32   = 262144 B
  unsigned short* Xb = (unsigned short*)(ws + 9699328);         // 8192*768 bf16 = 12582912 B

  conv_w<<<96, 256, 0, stream>>>(W, WbT);
  xconv<<<512, 256, 0, stream>>>(X, Xb);
  gemm_xw<<<dim3(128, 8), 256, 0, stream>>>(Xb, WbT, a, mask, WhT, srcT, dstT);
  gat_attn<<<dim3(64, 16), 256, 0, stream>>>(WhT, srcT, dstT, out);
}